// Round 8
// baseline (361.900 us; speedup 1.0000x reference)
//
#include <hip/hip_runtime.h>
#include <hip/hip_bf16.h>

#define DEVI __device__ __forceinline__

typedef __attribute__((ext_vector_type(8))) short short8;   // 8 bf16 = 4 VGPRs (MFMA A/B frag)
typedef __attribute__((ext_vector_type(4))) float f32x4;    // MFMA C/D frag

constexpr int D    = 2048;
constexpr int DFF  = 5632;
constexpr int NTOK = 2048;   // total tokens (1024 MoE + 1024 dense)
constexpr int NMOE = 1024;
constexpr float KSCALE = 2.0f;  // 32/16

// up-GEMM N layout: [0,5632)=W1, [5632,11264)=W3, then LoRA-A columns:
constexpr int NW      = 11648;  // = 91*128
constexpr int COL_A1  = 11264;  // A1 stack: col = COL_A1 + e*16 + r
constexpr int COL_A3  = 11392;
constexpr int COL_LA1 = 11520;
constexpr int COL_LA3 = 11536;  // [11552,11648) zero-padded

DEVI float bf2f(unsigned short u) { return __uint_as_float(((unsigned)u) << 16); }
DEVI unsigned short f2bf(float f) {                       // round-to-nearest-even
  unsigned u = __float_as_uint(f);
  u += 0x7FFFu + ((u >> 16) & 1u);
  return (unsigned short)(u >> 16);
}
DEVI float silu(float x) { return x / (1.f + __expf(-x)); }

// ---------------------------------------------------------------- prep: f32->bf16 casts
struct CastSegs {
  const float* src[14];
  unsigned short* dst[14];
  int blk_end[14];   // exclusive prefix sums of per-segment block counts
};

__global__ __launch_bounds__(256) void cast_segs_kernel(CastSegs cs) {
  int b = blockIdx.x;
  int s = 0;
  #pragma unroll
  for (int i = 0; i < 14; ++i) if (b >= cs.blk_end[i]) s = i + 1;
  int bstart = (s == 0) ? 0 : cs.blk_end[s - 1];
  size_t idx = ((size_t)(b - bstart) * 256 + threadIdx.x) * 4;   // every segment n % 1024 == 0
  float4 v = *(const float4*)(cs.src[s] + idx);
  ushort4 o;
  o.x = f2bf(v.x); o.y = f2bf(v.y); o.z = f2bf(v.z); o.w = f2bf(v.w);
  *(ushort4*)(cs.dst[s] + idx) = o;
}

// A2 (E,R,DFF) -> A2t (E,DFF,R) bf16 ; la2 (R,DFF) -> la2t (DFF,R) bf16
__global__ __launch_bounds__(256) void transpose_ra_kernel(const float* __restrict__ A2,
                                                           const float* __restrict__ la2,
                                                           unsigned short* __restrict__ A2tb,
                                                           unsigned short* __restrict__ la2tb) {
  int f = blockIdx.x * 256 + threadIdx.x;          // 0..5631 (grid.x=22 exact)
  int e = blockIdx.y;                              // 0..7 = A2 expert, 8 = la2
  const float* src = (e < 8) ? (A2 + (size_t)e * 16 * DFF) : la2;
  unsigned short* dst = (e < 8) ? (A2tb + (size_t)e * DFF * 16) : la2tb;
  unsigned short tmp[16];
  #pragma unroll
  for (int r = 0; r < 16; ++r) tmp[r] = f2bf(src[(size_t)r * DFF + f]);
  #pragma unroll
  for (int r = 0; r < 16; ++r) dst[(size_t)f * 16 + r] = tmp[r];
}

// ---------------------------------------------------------------- gating (exact f32)
__global__ __launch_bounds__(256) void gate_kernel(const float* __restrict__ x,
                                                   const float* __restrict__ gW,
                                                   float* __restrict__ logits_out,
                                                   int* __restrict__ gidx,
                                                   float* __restrict__ gwt) {
  int t = blockIdx.x * 4 + (threadIdx.x >> 6);     // one wave per token, 1024 tokens
  int lane = threadIdx.x & 63;
  const float* xr = x + (size_t)t * D;
  float acc[8];
  #pragma unroll
  for (int e = 0; e < 8; ++e) acc[e] = 0.f;
  for (int k = lane; k < D; k += 64) {
    float xv = xr[k];
    #pragma unroll
    for (int e = 0; e < 8; ++e) acc[e] = fmaf(xv, gW[e * D + k], acc[e]);
  }
  #pragma unroll
  for (int e = 0; e < 8; ++e) {
    float v = acc[e];
    #pragma unroll
    for (int s = 32; s > 0; s >>= 1) v += __shfl_xor(v, s);
    acc[e] = v;
  }
  if (lane == 0) {
    #pragma unroll
    for (int e = 0; e < 8; ++e) logits_out[(size_t)t * 8 + e] = acc[e];
    int i1 = 0;
    #pragma unroll
    for (int e = 1; e < 8; ++e) if (acc[e] > acc[i1]) i1 = e;   // ties -> lowest index (jax)
    int i2 = (i1 == 0) ? 1 : 0;
    #pragma unroll
    for (int e = 0; e < 8; ++e) if (e != i1 && acc[e] > acc[i2]) i2 = e;
    float w1 = 1.f / (1.f + expf(acc[i2] - acc[i1]));           // p1/(p1+p2), stable
    gidx[t * 2] = i1; gidx[t * 2 + 1] = i2;
    gwt[t * 2] = w1;  gwt[t * 2 + 1] = 1.f - w1;
  }
}

// ---------------------------------------------------------------- fine-interleaved bf16 GEMM
// C = A(M,K) * B(N,K)^T.  BK=64, per-wave 64x64 output (FM=FN=4), double-buffered LDS,
// per K-tile: gate {stage A(t+1), counted vmcnt(4), barrier} then 2 phases of
// {ds_read subtile || stage B-half -> barrier -> lgkmcnt(0)+sched_barrier ->
//  setprio'd 16-MFMA cluster}, trailing barrier.  XOR-swizzled LDS (granule^row&7,
// inverse applied on global source).  EPI: 1 -> bf16 store; 2 -> f32 store (+addv).
typedef const void __attribute__((address_space(1)))* gp1_t;
typedef void __attribute__((address_space(3)))* lp3_t;
DEVI void gload_lds16(const void* g, void* l) {
  __builtin_amdgcn_global_load_lds((gp1_t)g, (lp3_t)l, 16, 0, 0);
}
#define S_BARRIER() asm volatile("s_barrier" ::: "memory")
#define LGKM0() do { asm volatile("s_waitcnt lgkmcnt(0)" ::: "memory"); \
                     __builtin_amdgcn_sched_barrier(0); } while (0)

template <int N> DEVI void vmcnt_() {
  static_assert(N == 0 || N == 4, "enumerate literals");
  if constexpr (N == 0)  asm volatile("s_waitcnt vmcnt(0)" ::: "memory");
  if constexpr (N == 4)  asm volatile("s_waitcnt vmcnt(4)" ::: "memory");
}

template <int BM, int BN, int WM, int WN, int MINW, int EPI>
__global__ __launch_bounds__(WM * WN * 64, MINW) void gemmP(
    const unsigned short* __restrict__ A,
    const unsigned short* __restrict__ B,
    int K,
    float* __restrict__ Cf,
    unsigned short* __restrict__ Cb,
    const float* __restrict__ addv,
    int ldc, int nbx) {
  constexpr int THREADS = WM * WN * 64;
  constexpr int RW = BM / WM;              // 64
  constexpr int CW = BN / WN;              // 64
  static_assert(RW == 64 && CW == 64, "template assumes 64x64 per-wave tile");
  constexpr int ATILE = BM * 128;          // bytes (BM x 64 bf16)
  constexpr int BTILE = BN * 128;
  constexpr int SLOT = ATILE + BTILE;
  constexpr int APARTS = BM * 8 / THREADS; // 16B chunks per thread for A
  constexpr int BPARTS = BN * 8 / THREADS;
  constexpr int BH = BPARTS / 2;           // B chunks per half
  static_assert(APARTS == 4, "vmcnt gate literal assumes 4 A-loads");

  __shared__ __align__(16) char smem[2 * SLOT];

  const int tid = threadIdx.x;
  const int wave = tid >> 6, lane = tid & 63;
  const int wm = wave / WN, wn = wave % WN;
  const int r15 = lane & 15, g = lane >> 4;

  // XCD-aware bijective block swizzle (nwg % 8 == 0 for all our launches)
  const int nwg = (int)gridDim.x;
  const int bid = (int)blockIdx.x;
  const int wgid = (bid & 7) * (nwg >> 3) + (bid >> 3);
  const int bx = wgid % nbx, by = wgid / nbx;

  const unsigned short* Ablk = A + (size_t)by * BM * K;
  const unsigned short* Bblk = B + (size_t)bx * BN * K;

  // staging precompute: thread covers 16B chunk tt=j*THREADS+tid; row=tt>>3;
  // global source col pre-inverse-swizzled so linear LDS dest + swizzled read match.
  int sgoA[APARTS], sgoB[BPARTS];
  #pragma unroll
  for (int j = 0; j < APARTS; ++j) {
    int tt = j * THREADS + tid;
    int row = tt >> 3;
    sgoA[j] = row * K + (((tt & 7) ^ (row & 7)) << 3);
  }
  #pragma unroll
  for (int j = 0; j < BPARTS; ++j) {
    int tt = j * THREADS + tid;
    int row = tt >> 3;
    sgoB[j] = row * K + (((tt & 7) ^ (row & 7)) << 3);
  }
  auto stageA = [&](int p, int k0) {
    char* s = smem + p * SLOT;
    #pragma unroll
    for (int j = 0; j < APARTS; ++j)
      gload_lds16((const char*)Ablk + ((size_t)(sgoA[j] + k0) << 1),
                  s + j * (THREADS * 16) + wave * 1024);
  };
  auto stageBh = [&](int p, int k0, int h) {
    char* s = smem + p * SLOT + ATILE;
    #pragma unroll
    for (int j = 0; j < BH; ++j)
      gload_lds16((const char*)Bblk + ((size_t)(sgoB[h * BH + j] + k0) << 1),
                  s + (h * BH + j) * (THREADS * 16) + wave * 1024);
  };

  // ds_read addressing (swizzled): row*128 + ((granule ^ (row&7))<<4)
  const int arow0 = (wm * RW + r15) * 128;
  const int brow0 = (wn * CW + r15) * 128;
  const int s0 = ((g ^ (r15 & 7)) << 4);
  const int s1 = (((4 + g) ^ (r15 & 7)) << 4);

  f32x4 acc[4][4];
  #pragma unroll
  for (int m = 0; m < 4; ++m)
    #pragma unroll
    for (int n = 0; n < 4; ++n)
      #pragma unroll
      for (int j = 0; j < 4; ++j) acc[m][n][j] = 0.f;

  const int NT = K >> 6;

  // prologue: tile 0 fully into buf 0
  stageA(0, 0);
  stageBh(0, 0, 0);
  stageBh(0, 0, 1);

  for (int t = 0; t < NT; ++t) {
    const int p = t & 1;
    const bool hn = (t + 1) < NT;
    const int k0n = (t + 1) << 6;
    // ---- gate: issue A(t+1), counted wait for tile t's loads, sync
    if (hn) {
      stageA(p ^ 1, k0n);
      vmcnt_<4>();                          // tile t's loads (oldest) landed
    } else {
      vmcnt_<0>();
    }
    S_BARRIER();

    const char* sA = smem + p * SLOT;
    const char* sB = sA + ATILE;

    // ---- phase a: read B-all + A m0-1 ; stage B-half0 ; MFMA (m0-1 x n0-3)
    short8 bq[4][2], af[2][2];
    #pragma unroll
    for (int n = 0; n < 4; ++n) {
      bq[n][0] = *(const short8*)(sB + brow0 + n * 2048 + s0);
      bq[n][1] = *(const short8*)(sB + brow0 + n * 2048 + s1);
    }
    #pragma unroll
    for (int i = 0; i < 2; ++i) {
      af[i][0] = *(const short8*)(sA + arow0 + i * 2048 + s0);
      af[i][1] = *(const short8*)(sA + arow0 + i * 2048 + s1);
    }
    if (hn) stageBh(p ^ 1, k0n, 0);
    S_BARRIER();
    LGKM0();
    __builtin_amdgcn_s_setprio(1);
    #pragma unroll
    for (int i = 0; i < 2; ++i)
      #pragma unroll
      for (int n = 0; n < 4; ++n)
        #pragma unroll
        for (int kk = 0; kk < 2; ++kk)
          acc[i][n] = __builtin_amdgcn_mfma_f32_16x16x32_bf16(
              af[i][kk], bq[n][kk], acc[i][n], 0, 0, 0);
    __builtin_amdgcn_s_setprio(0);

    // ---- phase b: read A m2-3 ; stage B-half1 ; MFMA (m2-3 x n0-3)
    short8 ag[2][2];
    #pragma unroll
    for (int i = 0; i < 2; ++i) {
      ag[i][0] = *(const short8*)(sA + arow0 + (2 + i) * 2048 + s0);
      ag[i][1] = *(const short8*)(sA + arow0 + (2 + i) * 2048 + s1);
    }
    if (hn) stageBh(p ^ 1, k0n, 1);
    S_BARRIER();
    LGKM0();
    __builtin_amdgcn_s_setprio(1);
    #pragma unroll
    for (int i = 0; i < 2; ++i)
      #pragma unroll
      for (int n = 0; n < 4; ++n)
        #pragma unroll
        for (int kk = 0; kk < 2; ++kk)
          acc[2 + i][n] = __builtin_amdgcn_mfma_f32_16x16x32_bf16(
              ag[i][kk], bq[n][kk], acc[2 + i][n], 0, 0, 0);
    __builtin_amdgcn_s_setprio(0);

    S_BARRIER();        // all reads of buf p done before next gate overwrites it
  }

  // epilogue: C/D layout col=lane&15, row=(lane>>4)*4+reg  [m89-verified]
  const int row0 = by * BM + wm * RW + (g << 2);
  const int col0 = bx * BN + wn * CW + r15;
  #pragma unroll
  for (int m = 0; m < 4; ++m) {
    #pragma unroll
    for (int n = 0; n < 4; ++n) {
      int col = col0 + n * 16;
      #pragma unroll
      for (int j = 0; j < 4; ++j) {
        int row = row0 + m * 16 + j;
        size_t off = (size_t)row * ldc + col;
        float v = acc[m][n][j];
        if (EPI == 1) Cb[off] = f2bf(v);
        else          Cf[off] = v + addv[off];
      }
    }
  }
}

// ---------------------------------------------------------------- h / combine / q kernel
DEVI float dot16bf(const float* a, const unsigned short* w) {
  short8 w0 = *(const short8*)w;
  short8 w1 = *(const short8*)(w + 8);
  float s = 0.f;
  #pragma unroll
  for (int i = 0; i < 8; ++i) s = fmaf(a[i],     bf2f((unsigned short)w0[i]), s);
  #pragma unroll
  for (int i = 0; i < 8; ++i) s = fmaf(a[8 + i], bf2f((unsigned short)w1[i]), s);
  return s;
}

__global__ __launch_bounds__(256) void h_kernel(
    const unsigned short* __restrict__ GU,      // [NTOK][NW] bf16
    const unsigned short* __restrict__ B1b,     // [8][DFF][16]
    const unsigned short* __restrict__ B3b,
    const unsigned short* __restrict__ A2tb,    // [8][DFF][16]
    const unsigned short* __restrict__ lb1b,    // [DFF][16]
    const unsigned short* __restrict__ lb3b,
    const unsigned short* __restrict__ la2tb,   // [DFF][16]
    const int* __restrict__ gidx, const float* __restrict__ gwt,
    unsigned short* __restrict__ Hb,            // [NTOK][DFF] bf16
    float* __restrict__ qw) {                   // [NTOK][32]
  const int t = blockIdx.x;
  const int tid = threadIdx.x;
  const unsigned short* gu = GU + (size_t)t * NW;
  unsigned short* hrow = Hb + (size_t)t * DFF;
  float qacc[32];
  #pragma unroll
  for (int r = 0; r < 32; ++r) qacc[r] = 0.f;
  float w1 = 0.f, w2 = 0.f;

  if (t < NMOE) {
    const int e1 = gidx[t * 2], e2 = gidx[t * 2 + 1];
    w1 = gwt[t * 2]; w2 = gwt[t * 2 + 1];
    float xa1a[16], xa1b[16], xa3a[16], xa3b[16];
    #pragma unroll
    for (int r = 0; r < 16; ++r) {
      xa1a[r] = bf2f(gu[COL_A1 + e1 * 16 + r]);
      xa1b[r] = bf2f(gu[COL_A1 + e2 * 16 + r]);
      xa3a[r] = bf2f(gu[COL_A3 + e1 * 16 + r]);
      xa3b[r] = bf2f(gu[COL_A3 + e2 * 16 + r]);
    }
    const unsigned short* B1e1 = B1b + (size_t)e1 * DFF * 16;
    const unsigned short* B1e2 = B1b + (size_t)e2 * DFF * 16;
    const unsigned short* B3e1 = B3b + (size_t)e1 * DFF * 16;
    const unsigned short* B3e2 = B3b + (size_t)e2 * DFF * 16;
    const unsigned short* A2e1 = A2tb + (size_t)e1 * DFF * 16;
    const unsigned short* A2e2 = A2tb + (size_t)e2 * DFF * 16;
    for (int i = 0; i < 22; ++i) {
      int f = tid + i * 256;
      float bg = bf2f(gu[f]), bu = bf2f(gu[DFF + f]);
      float dg1 = dot16bf(xa1a, B1e1 + f * 16);
      float du1 = dot16bf(xa3a, B3e1 + f * 16);
      float dg2 = dot16bf(xa1b, B1e2 + f * 16);
      float du2 = dot16bf(xa3b, B3e2 + f * 16);
      float h1 = silu(bg + KSCALE * dg1) * (bu + KSCALE * du1);
      float h2 = silu(bg + KSCALE * dg2) * (bu + KSCALE * du2);
      hrow[f] = f2bf(w1 * h1 + w2 * h2);
      short8 a0 = *(const short8*)(A2e1 + f * 16);
      short8 a1 = *(const short8*)(A2e1 + f * 16 + 8);
      short8 b0 = *(const short8*)(A2e2 + f * 16);
      short8 b1 = *(const short8*)(A2e2 + f * 16 + 8);
      #pragma unroll
      for (int r = 0; r < 8; ++r) {
        qacc[r]      = fmaf(h1, bf2f((unsigned short)a0[r]), qacc[r]);
        qacc[8 + r]  = fmaf(h1, bf2f((unsigned short)a1[r]), qacc[8 + r]);
        qacc[16 + r] = fmaf(h2, bf2f((unsigned short)b0[r]), qacc[16 + r]);
        qacc[24 + r] = fmaf(h2, bf2f((unsigned short)b1[r]), qacc[24 + r]);
      }
    }
  } else {
    float s1[16], s3[16];
    #pragma unroll
    for (int r = 0; r < 16; ++r) {
      s1[r] = bf2f(gu[COL_LA1 + r]);
      s3[r] = bf2f(gu[COL_LA3 + r]);
    }
    for (int i = 0; i < 22; ++i) {
      int f = tid + i * 256;
      float bg = bf2f(gu[f]), bu = bf2f(gu[DFF + f]);
      float dg = dot16bf(s1, lb1b + f * 16);
      float du = dot16bf(s3, lb3b + f * 16);
      float h = silu(bg + KSCALE * dg) * (bu + KSCALE * du);
      hrow[f] = f2bf(h);
      short8 a0 = *(const short8*)(la2tb + f * 16);
      short8 a1 = *(const short8*)(la2tb + f * 16 + 8);
      #pragma unroll
      for (int r = 0; r < 8; ++r) {
        qacc[r]     = fmaf(h, bf2f((unsigned short)a0[r]), qacc[r]);
        qacc[8 + r] = fmaf(h, bf2f((unsigned short)a1[r]), qacc[8 + r]);
      }
    }
  }

  // reduce 32 partials across 256 threads
  #pragma unroll
  for (int r = 0; r < 32; ++r) {
    float v = qacc[r];
    #pragma unroll
    for (int s = 32; s > 0; s >>= 1) v += __shfl_xor(v, s);
    qacc[r] = v;
  }
  __shared__ float red[4][32];
  const int wave = tid >> 6, lane = tid & 63;
  if (lane == 0) {
    #pragma unroll
    for (int r = 0; r < 32; ++r) red[wave][r] = qacc[r];
  }
  __syncthreads();
  if (tid < 32) {
    float v = red[0][tid] + red[1][tid] + red[2][tid] + red[3][tid];
    float sc = (t < NMOE) ? ((tid < 16) ? (KSCALE * w1) : (KSCALE * w2)) : KSCALE;
    qw[(size_t)t * 32 + tid] = v * sc;
  }
}

// ---------------------------------------------------------------- rank-16 down-LoRA -> y_lora f32
__global__ __launch_bounds__(256) void ylora_kernel(const float* __restrict__ qw,
                                                    const unsigned short* __restrict__ B2b,   // [8][D][16]
                                                    const unsigned short* __restrict__ lb2b,  // [D][16]
                                                    const int* __restrict__ gidx,
                                                    float* __restrict__ ylora) {
  const int t = blockIdx.x;
  const int tid = threadIdx.x;
  const float* qr = qw + (size_t)t * 32;
  float q1[16], q2[16];
  #pragma unroll
  for (int r = 0; r < 16; ++r) { q1[r] = qr[r]; q2[r] = qr[16 + r]; }
  if (t < NMOE) {
    const unsigned short* p1 = B2b + (size_t)gidx[t * 2] * D * 16;
    const unsigned short* p2 = B2b + (size_t)gidx[t * 2 + 1] * D * 16;
    #pragma unroll
    for (int i = 0; i < 8; ++i) {
      int d = tid + i * 256;
      ylora[(size_t)t * D + d] = dot16bf(q1, p1 + d * 16) + dot16bf(q2, p2 + d * 16);
    }
  } else {
    #pragma unroll
    for (int i = 0; i < 8; ++i) {
      int d = tid + i * 256;
      ylora[(size_t)t * D + d] = dot16bf(q1, lb2b + d * 16);
    }
  }
}

// ---------------------------------------------------------------- host
extern "C" void kernel_launch(void* const* d_in, const int* in_sizes, int n_in,
                              void* d_out, int out_size, void* d_ws, size_t ws_size,
                              hipStream_t stream) {
  (void)in_sizes; (void)n_in; (void)out_size; (void)ws_size;
  const float* data = (const float*)d_in[0];
  const float* W1   = (const float*)d_in[1];
  const float* W3   = (const float*)d_in[2];
  const float* W2   = (const float*)d_in[3];
  const float* gW   = (const float*)d_in[4];
  const float* A1   = (const float*)d_in[5];
  const float* B1   = (const float*)d_in[6];
  const float* A3   = (const float*)d_in[7];
  const float* B3   = (const float*)d_in[8];
  const float* A2   = (const float*)d_in[9];
  const float* B2   = (const float*)d_in[10];
  const float* la1  = (const float*)d_in[11];
  const float* lb1  = (const float*)d_in[12];
  const float* la3  = (const float*)d_in[13];
  const float* lb3  = (const float*)d_in[14];
  const float* la2  = (const float*)d_in[15];
  const float* lb2  = (const float*)d_in[16];

  char* w = (char*)d_ws;
  size_t off = 0;
  auto alloc = [&](size_t bytes) -> char* {
    char* p = w + off;
    off += (bytes + 255) & ~(size_t)255;
    return p;
  };
  unsigned short* xb    = (unsigned short*)alloc((size_t)NTOK * D * 2);       // 8.4 MB
  unsigned short* W13b  = (unsigned short*)alloc((size_t)NW * D * 2);         // 47.7 MB (W1|W3|LoRA-A|pad)
  unsigned short* W2b   = (unsigned short*)alloc((size_t)D * DFF * 2);        // 23.1 MB
  unsigned short* B1b   = (unsigned short*)alloc((size_t)8 * DFF * 16 * 2);
  unsigned short* B3b   = (unsigned short*)alloc((size_t)8 * DFF * 16 * 2);
  unsigned short* A2tb  = (unsigned short*)alloc((size_t)8 * DFF * 16 * 2);
  unsigned short* la2tb = (unsigned short*)alloc((size_t)DFF * 16 * 2);
  unsigned short* lb1b  = (unsigned short*)alloc((size_t)DFF * 16 * 2);
  unsigned short* lb3b  = (unsigned short*)alloc((size_t)DFF * 16 * 2);
  unsigned short* lb2b  = (unsigned short*)alloc((size_t)D * 16 * 2);
  unsigned short* B2b   = (unsigned short*)alloc((size_t)8 * D * 16 * 2);
  int*   gidx = (int*)alloc((size_t)NMOE * 2 * 4);
  float* gwt  = (float*)alloc((size_t)NMOE * 2 * 4);
  unsigned short* GU    = (unsigned short*)alloc((size_t)NTOK * NW * 2);      // 47.7 MB

  // Aliased scratch (regions dead after the up-GEMM):
  unsigned short* Hb = W13b;                                        // 23.07 MB into W1 region
  float* ylora = (float*)((char*)W13b + (size_t)NTOK * DFF * 2);    // 16.78 MB into W3 region
  float* qw    = (float*)xb;                                        // 0.26 MB

  // ---- prep casts (all n % 1024 == 0)
  CastSegs cs;
  const float* srcs[14] = {data, W1, W3, W2, A1, A3, la1, la3, B1, B3, lb1, lb3, lb2, B2};
  unsigned short* dsts[14] = {
      xb, W13b, W13b + (size_t)DFF * D, W2b,
      W13b + (size_t)COL_A1 * D, W13b + (size_t)COL_A3 * D,
      W13b + (size_t)COL_LA1 * D, W13b + (size_t)COL_LA3 * D,
      B1b, B3b, lb1b, lb3b, lb2b, B2b};
  int ns[14] = {NTOK * D, DFF * D, DFF * D, DFF * D, 128 * D, 128 * D, 16 * D, 16 * D,
                8 * DFF * 16, 8 * DFF * 16, DFF * 16, DFF * 16, D * 16, 8 * D * 16};
  int total_blocks = 0;
  for (int i = 0; i < 14; ++i) {
    cs.src[i] = srcs[i];
    cs.dst[i] = dsts[i];
    total_blocks += ns[i] / 1024;
    cs.blk_end[i] = total_blocks;
  }
  cast_segs_kernel<<<total_blocks, 256, 0, stream>>>(cs);
  transpose_ra_kernel<<<dim3(DFF / 256, 9), 256, 0, stream>>>(A2, la2, A2tb, la2tb);
  hipMemsetAsync(W13b + (size_t)11552 * D, 0, (size_t)(NW - 11552) * D * 2, stream);  // zero-pad rows

  // ---- gating (also writes logits output, f32)
  gate_kernel<<<NMOE / 4, 256, 0, stream>>>(data, gW,
      (float*)d_out + (size_t)NTOK * D, gidx, gwt);

  // ---- up-GEMM: [X | LoRA-A] fused, 2048 x 11648 x 2048, bf16 out -> GU
  // 128x128, 4 waves of 64x64, dbuf 64KB -> 2 blocks/CU resident, grid 1456 (5.7 rounds)
  gemmP<128, 128, 2, 2, 2, 1><<<(NTOK / 128) * (NW / 128), 256, 0, stream>>>(
      xb, W13b, D, (float*)nullptr, GU, (const float*)nullptr, NW, NW / 128);

  // ---- h̄ / per-expert q  (writes Hb, qw — aliased into now-dead regions)
  h_kernel<<<NTOK, 256, 0, stream>>>(GU, B1b, B3b, A2tb, lb1b, lb3b, la2tb,
                                     gidx, gwt, Hb, qw);

  // ---- rank-16 down-LoRA correction
  ylora_kernel<<<NTOK, 256, 0, stream>>>(qw, B2b, lb2b, gidx, ylora);

  // ---- down-GEMM: 2048 x 2048 x 5632, epilogue adds y_lora, f32 -> d_out
  // 128x128, 4 waves of 64x64, dbuf 64KB, fine-interleaved, grid 256
  gemmP<128, 128, 2, 2, 2, 2><<<(NTOK / 128) * (D / 128), 256, 0, stream>>>(
      Hb, W2b, DFF, (float*)d_out, (unsigned short*)nullptr, ylora, D, D / 128);
}

// Round 9
// 351.716 us; speedup vs baseline: 1.0290x; 1.0290x over previous
//
#include <hip/hip_runtime.h>
#include <hip/hip_bf16.h>

#define DEVI __device__ __forceinline__

typedef __attribute__((ext_vector_type(8))) short short8;   // 8 bf16 = 4 VGPRs (MFMA A/B frag)
typedef __attribute__((ext_vector_type(4))) float f32x4;    // MFMA C/D frag

constexpr int D    = 2048;
constexpr int DFF  = 5632;
constexpr int NTOK = 2048;   // total tokens (1024 MoE + 1024 dense)
constexpr int NMOE = 1024;
constexpr float KSCALE = 2.0f;  // 32/16

// up-GEMM N layout: [0,5632)=W1, [5632,11264)=W3, then LoRA-A columns:
constexpr int NW      = 11648;  // = 91*128
constexpr int COL_A1  = 11264;  // A1 stack: col = COL_A1 + e*16 + r
constexpr int COL_A3  = 11392;
constexpr int COL_LA1 = 11520;
constexpr int COL_LA3 = 11536;  // [11552,11648) zero-padded

DEVI float bf2f(unsigned short u) { return __uint_as_float(((unsigned)u) << 16); }
DEVI unsigned short f2bf(float f) {                       // round-to-nearest-even
  unsigned u = __float_as_uint(f);
  u += 0x7FFFu + ((u >> 16) & 1u);
  return (unsigned short)(u >> 16);
}
DEVI float silu(float x) { return x / (1.f + __expf(-x)); }

// ---------------------------------------------------------------- prep: f32->bf16 casts
struct CastSegs {
  const float* src[14];
  unsigned short* dst[14];
  int blk_end[14];   // exclusive prefix sums of per-segment block counts
};

__global__ __launch_bounds__(256) void cast_segs_kernel(CastSegs cs) {
  int b = blockIdx.x;
  int s = 0;
  #pragma unroll
  for (int i = 0; i < 14; ++i) if (b >= cs.blk_end[i]) s = i + 1;
  int bstart = (s == 0) ? 0 : cs.blk_end[s - 1];
  size_t idx = ((size_t)(b - bstart) * 256 + threadIdx.x) * 4;   // every segment n % 1024 == 0
  float4 v = *(const float4*)(cs.src[s] + idx);
  ushort4 o;
  o.x = f2bf(v.x); o.y = f2bf(v.y); o.z = f2bf(v.z); o.w = f2bf(v.w);
  *(ushort4*)(cs.dst[s] + idx) = o;
}

// A2 (E,R,DFF) -> A2t (E,DFF,R) bf16 ; la2 (R,DFF) -> la2t (DFF,R) bf16
__global__ __launch_bounds__(256) void transpose_ra_kernel(const float* __restrict__ A2,
                                                           const float* __restrict__ la2,
                                                           unsigned short* __restrict__ A2tb,
                                                           unsigned short* __restrict__ la2tb) {
  int f = blockIdx.x * 256 + threadIdx.x;          // 0..5631 (grid.x=22 exact)
  int e = blockIdx.y;                              // 0..7 = A2 expert, 8 = la2
  const float* src = (e < 8) ? (A2 + (size_t)e * 16 * DFF) : la2;
  unsigned short* dst = (e < 8) ? (A2tb + (size_t)e * DFF * 16) : la2tb;
  unsigned short tmp[16];
  #pragma unroll
  for (int r = 0; r < 16; ++r) tmp[r] = f2bf(src[(size_t)r * DFF + f]);
  #pragma unroll
  for (int r = 0; r < 16; ++r) dst[(size_t)f * 16 + r] = tmp[r];
}

// ---------------------------------------------------------------- gating (exact f32)
__global__ __launch_bounds__(256) void gate_kernel(const float* __restrict__ x,
                                                   const float* __restrict__ gW,
                                                   float* __restrict__ logits_out,
                                                   int* __restrict__ gidx,
                                                   float* __restrict__ gwt) {
  int t = blockIdx.x * 4 + (threadIdx.x >> 6);     // one wave per token, 1024 tokens
  int lane = threadIdx.x & 63;
  const float* xr = x + (size_t)t * D;
  float acc[8];
  #pragma unroll
  for (int e = 0; e < 8; ++e) acc[e] = 0.f;
  for (int k = lane; k < D; k += 64) {
    float xv = xr[k];
    #pragma unroll
    for (int e = 0; e < 8; ++e) acc[e] = fmaf(xv, gW[e * D + k], acc[e]);
  }
  #pragma unroll
  for (int e = 0; e < 8; ++e) {
    float v = acc[e];
    #pragma unroll
    for (int s = 32; s > 0; s >>= 1) v += __shfl_xor(v, s);
    acc[e] = v;
  }
  if (lane == 0) {
    #pragma unroll
    for (int e = 0; e < 8; ++e) logits_out[(size_t)t * 8 + e] = acc[e];
    int i1 = 0;
    #pragma unroll
    for (int e = 1; e < 8; ++e) if (acc[e] > acc[i1]) i1 = e;   // ties -> lowest index (jax)
    int i2 = (i1 == 0) ? 1 : 0;
    #pragma unroll
    for (int e = 0; e < 8; ++e) if (e != i1 && acc[e] > acc[i2]) i2 = e;
    float w1 = 1.f / (1.f + expf(acc[i2] - acc[i1]));           // p1/(p1+p2), stable
    gidx[t * 2] = i1; gidx[t * 2 + 1] = i2;
    gwt[t * 2] = w1;  gwt[t * 2 + 1] = 1.f - w1;
  }
}

// ---------------------------------------------------------------- minimal-barrier bf16 GEMM
// C = A(M,K) * B(N,K)^T.  BK=64, per-wave 64x64 output, double-buffered LDS,
// per K-tile: {stage all 8 loads of tile t+1 -> counted vmcnt(8) -> barrier ->
// [16 ds_read + 32 MFMA, compiler-scheduled, NO pinning] -> barrier}.
// XOR-swizzled LDS (granule^row&7, inverse applied on global source) -> 0 conflicts.
// EPI: 1 -> bf16 store; 2 -> f32 store (+addv).
typedef const void __attribute__((address_space(1)))* gp1_t;
typedef void __attribute__((address_space(3)))* lp3_t;
DEVI void gload_lds16(const void* g, void* l) {
  __builtin_amdgcn_global_load_lds((gp1_t)g, (lp3_t)l, 16, 0, 0);
}
#define S_BARRIER() asm volatile("s_barrier" ::: "memory")

template <int N> DEVI void vmcnt_() {
  static_assert(N == 0 || N == 8, "enumerate literals");
  if constexpr (N == 0) asm volatile("s_waitcnt vmcnt(0)" ::: "memory");
  if constexpr (N == 8) asm volatile("s_waitcnt vmcnt(8)" ::: "memory");
}

template <int BM, int BN, int WM, int WN, int MINW, int EPI>
__global__ __launch_bounds__(WM * WN * 64, MINW) void gemmM(
    const unsigned short* __restrict__ A,
    const unsigned short* __restrict__ B,
    int K,
    float* __restrict__ Cf,
    unsigned short* __restrict__ Cb,
    const float* __restrict__ addv,
    int ldc, int nbx) {
  constexpr int THREADS = WM * WN * 64;
  constexpr int RW = BM / WM;              // 64
  constexpr int CW = BN / WN;              // 64
  static_assert(RW == 64 && CW == 64, "template assumes 64x64 per-wave tile");
  constexpr int ATILE = BM * 128;          // bytes (BM x 64 bf16)
  constexpr int BTILE = BN * 128;
  constexpr int SLOT = ATILE + BTILE;
  constexpr int APARTS = BM * 8 / THREADS; // 16B chunks per thread for A
  constexpr int BPARTS = BN * 8 / THREADS;
  static_assert(APARTS + BPARTS == 8, "vmcnt gate literal assumes 8 loads/tile");

  __shared__ __align__(16) char smem[2 * SLOT];

  const int tid = threadIdx.x;
  const int wave = tid >> 6, lane = tid & 63;
  const int wm = wave / WN, wn = wave % WN;
  const int r15 = lane & 15, g = lane >> 4;

  // XCD-aware bijective block swizzle (nwg % 8 == 0 for all our launches)
  const int nwg = (int)gridDim.x;
  const int bid = (int)blockIdx.x;
  const int wgid = (bid & 7) * (nwg >> 3) + (bid >> 3);
  const int bx = wgid % nbx, by = wgid / nbx;

  const unsigned short* Ablk = A + (size_t)by * BM * K;
  const unsigned short* Bblk = B + (size_t)bx * BN * K;

  // staging precompute: thread covers 16B chunk tt=j*THREADS+tid; row=tt>>3;
  // global source col pre-inverse-swizzled so linear LDS dest + swizzled read match.
  int sgoA[APARTS], sgoB[BPARTS];
  #pragma unroll
  for (int j = 0; j < APARTS; ++j) {
    int tt = j * THREADS + tid;
    int row = tt >> 3;
    sgoA[j] = row * K + (((tt & 7) ^ (row & 7)) << 3);
  }
  #pragma unroll
  for (int j = 0; j < BPARTS; ++j) {
    int tt = j * THREADS + tid;
    int row = tt >> 3;
    sgoB[j] = row * K + (((tt & 7) ^ (row & 7)) << 3);
  }
  auto stage = [&](int p, int k0) {
    char* s = smem + p * SLOT;
    #pragma unroll
    for (int j = 0; j < APARTS; ++j)
      gload_lds16((const char*)Ablk + ((size_t)(sgoA[j] + k0) << 1),
                  s + j * (THREADS * 16) + wave * 1024);
    #pragma unroll
    for (int j = 0; j < BPARTS; ++j)
      gload_lds16((const char*)Bblk + ((size_t)(sgoB[j] + k0) << 1),
                  s + ATILE + j * (THREADS * 16) + wave * 1024);
  };

  // ds_read addressing (swizzled): row*128 + ((granule ^ (row&7))<<4)
  const int arow0 = (wm * RW + r15) * 128;
  const int brow0 = (wn * CW + r15) * 128;
  const int s0 = ((g ^ (r15 & 7)) << 4);
  const int s1 = (((4 + g) ^ (r15 & 7)) << 4);

  f32x4 acc[4][4];
  #pragma unroll
  for (int m = 0; m < 4; ++m)
    #pragma unroll
    for (int n = 0; n < 4; ++n)
      #pragma unroll
      for (int j = 0; j < 4; ++j) acc[m][n][j] = 0.f;

  const int NT = K >> 6;

  stage(0, 0);                              // prologue: tile 0 -> buf 0

  for (int t = 0; t < NT; ++t) {
    const int p = t & 1;
    if (t + 1 < NT) {
      stage(p ^ 1, (t + 1) << 6);           // 8 loads for tile t+1 (into freed buf)
      vmcnt_<8>();                          // tile t fully landed (8 newest = t+1's)
    } else {
      vmcnt_<0>();
    }
    S_BARRIER();                            // all waves: buf p valid

    const char* sA = smem + p * SLOT;
    const char* sB = sA + ATILE;

    // reads + MFMA, unpinned: compiler interleaves with fine-grained lgkmcnt
    short8 bq[4][2], av[4][2];
    #pragma unroll
    for (int n = 0; n < 4; ++n) {
      bq[n][0] = *(const short8*)(sB + brow0 + n * 2048 + s0);
      bq[n][1] = *(const short8*)(sB + brow0 + n * 2048 + s1);
    }
    #pragma unroll
    for (int m = 0; m < 4; ++m) {
      av[m][0] = *(const short8*)(sA + arow0 + m * 2048 + s0);
      av[m][1] = *(const short8*)(sA + arow0 + m * 2048 + s1);
    }
    #pragma unroll
    for (int m = 0; m < 4; ++m)
      #pragma unroll
      for (int n = 0; n < 4; ++n)
        #pragma unroll
        for (int kk = 0; kk < 2; ++kk)
          acc[m][n] = __builtin_amdgcn_mfma_f32_16x16x32_bf16(
              av[m][kk], bq[n][kk], acc[m][n], 0, 0, 0);

    S_BARRIER();                            // reads of buf p done before overwrite
  }

  // epilogue: C/D layout col=lane&15, row=(lane>>4)*4+reg  [m89-verified]
  const int row0 = by * BM + wm * RW + (g << 2);
  const int col0 = bx * BN + wn * CW + r15;
  #pragma unroll
  for (int m = 0; m < 4; ++m) {
    #pragma unroll
    for (int n = 0; n < 4; ++n) {
      int col = col0 + n * 16;
      #pragma unroll
      for (int j = 0; j < 4; ++j) {
        int row = row0 + m * 16 + j;
        size_t off = (size_t)row * ldc + col;
        float v = acc[m][n][j];
        if (EPI == 1) Cb[off] = f2bf(v);
        else          Cf[off] = v + addv[off];
      }
    }
  }
}

// ---------------------------------------------------------------- h / combine / q kernel
DEVI float dot16bf(const float* a, const unsigned short* w) {
  short8 w0 = *(const short8*)w;
  short8 w1 = *(const short8*)(w + 8);
  float s = 0.f;
  #pragma unroll
  for (int i = 0; i < 8; ++i) s = fmaf(a[i],     bf2f((unsigned short)w0[i]), s);
  #pragma unroll
  for (int i = 0; i < 8; ++i) s = fmaf(a[8 + i], bf2f((unsigned short)w1[i]), s);
  return s;
}

__global__ __launch_bounds__(256) void h_kernel(
    const unsigned short* __restrict__ GU,      // [NTOK][NW] bf16
    const unsigned short* __restrict__ B1b,     // [8][DFF][16]
    const unsigned short* __restrict__ B3b,
    const unsigned short* __restrict__ A2tb,    // [8][DFF][16]
    const unsigned short* __restrict__ lb1b,    // [DFF][16]
    const unsigned short* __restrict__ lb3b,
    const unsigned short* __restrict__ la2tb,   // [DFF][16]
    const int* __restrict__ gidx, const float* __restrict__ gwt,
    unsigned short* __restrict__ Hb,            // [NTOK][DFF] bf16
    float* __restrict__ qw) {                   // [NTOK][32]
  const int t = blockIdx.x;
  const int tid = threadIdx.x;
  const unsigned short* gu = GU + (size_t)t * NW;
  unsigned short* hrow = Hb + (size_t)t * DFF;
  float qacc[32];
  #pragma unroll
  for (int r = 0; r < 32; ++r) qacc[r] = 0.f;
  float w1 = 0.f, w2 = 0.f;

  if (t < NMOE) {
    const int e1 = gidx[t * 2], e2 = gidx[t * 2 + 1];
    w1 = gwt[t * 2]; w2 = gwt[t * 2 + 1];
    float xa1a[16], xa1b[16], xa3a[16], xa3b[16];
    #pragma unroll
    for (int r = 0; r < 16; ++r) {
      xa1a[r] = bf2f(gu[COL_A1 + e1 * 16 + r]);
      xa1b[r] = bf2f(gu[COL_A1 + e2 * 16 + r]);
      xa3a[r] = bf2f(gu[COL_A3 + e1 * 16 + r]);
      xa3b[r] = bf2f(gu[COL_A3 + e2 * 16 + r]);
    }
    const unsigned short* B1e1 = B1b + (size_t)e1 * DFF * 16;
    const unsigned short* B1e2 = B1b + (size_t)e2 * DFF * 16;
    const unsigned short* B3e1 = B3b + (size_t)e1 * DFF * 16;
    const unsigned short* B3e2 = B3b + (size_t)e2 * DFF * 16;
    const unsigned short* A2e1 = A2tb + (size_t)e1 * DFF * 16;
    const unsigned short* A2e2 = A2tb + (size_t)e2 * DFF * 16;
    for (int i = 0; i < 22; ++i) {
      int f = tid + i * 256;
      float bg = bf2f(gu[f]), bu = bf2f(gu[DFF + f]);
      float dg1 = dot16bf(xa1a, B1e1 + f * 16);
      float du1 = dot16bf(xa3a, B3e1 + f * 16);
      float dg2 = dot16bf(xa1b, B1e2 + f * 16);
      float du2 = dot16bf(xa3b, B3e2 + f * 16);
      float h1 = silu(bg + KSCALE * dg1) * (bu + KSCALE * du1);
      float h2 = silu(bg + KSCALE * dg2) * (bu + KSCALE * du2);
      hrow[f] = f2bf(w1 * h1 + w2 * h2);
      short8 a0 = *(const short8*)(A2e1 + f * 16);
      short8 a1 = *(const short8*)(A2e1 + f * 16 + 8);
      short8 b0 = *(const short8*)(A2e2 + f * 16);
      short8 b1 = *(const short8*)(A2e2 + f * 16 + 8);
      #pragma unroll
      for (int r = 0; r < 8; ++r) {
        qacc[r]      = fmaf(h1, bf2f((unsigned short)a0[r]), qacc[r]);
        qacc[8 + r]  = fmaf(h1, bf2f((unsigned short)a1[r]), qacc[8 + r]);
        qacc[16 + r] = fmaf(h2, bf2f((unsigned short)b0[r]), qacc[16 + r]);
        qacc[24 + r] = fmaf(h2, bf2f((unsigned short)b1[r]), qacc[24 + r]);
      }
    }
  } else {
    float s1[16], s3[16];
    #pragma unroll
    for (int r = 0; r < 16; ++r) {
      s1[r] = bf2f(gu[COL_LA1 + r]);
      s3[r] = bf2f(gu[COL_LA3 + r]);
    }
    for (int i = 0; i < 22; ++i) {
      int f = tid + i * 256;
      float bg = bf2f(gu[f]), bu = bf2f(gu[DFF + f]);
      float dg = dot16bf(s1, lb1b + f * 16);
      float du = dot16bf(s3, lb3b + f * 16);
      float h = silu(bg + KSCALE * dg) * (bu + KSCALE * du);
      hrow[f] = f2bf(h);
      short8 a0 = *(const short8*)(la2tb + f * 16);
      short8 a1 = *(const short8*)(la2tb + f * 16 + 8);
      #pragma unroll
      for (int r = 0; r < 8; ++r) {
        qacc[r]     = fmaf(h, bf2f((unsigned short)a0[r]), qacc[r]);
        qacc[8 + r] = fmaf(h, bf2f((unsigned short)a1[r]), qacc[8 + r]);
      }
    }
  }

  // reduce 32 partials across 256 threads
  #pragma unroll
  for (int r = 0; r < 32; ++r) {
    float v = qacc[r];
    #pragma unroll
    for (int s = 32; s > 0; s >>= 1) v += __shfl_xor(v, s);
    qacc[r] = v;
  }
  __shared__ float red[4][32];
  const int wave = tid >> 6, lane = tid & 63;
  if (lane == 0) {
    #pragma unroll
    for (int r = 0; r < 32; ++r) red[wave][r] = qacc[r];
  }
  __syncthreads();
  if (tid < 32) {
    float v = red[0][tid] + red[1][tid] + red[2][tid] + red[3][tid];
    float sc = (t < NMOE) ? ((tid < 16) ? (KSCALE * w1) : (KSCALE * w2)) : KSCALE;
    qw[(size_t)t * 32 + tid] = v * sc;
  }
}

// ---------------------------------------------------------------- rank-16 down-LoRA -> y_lora f32
__global__ __launch_bounds__(256) void ylora_kernel(const float* __restrict__ qw,
                                                    const unsigned short* __restrict__ B2b,   // [8][D][16]
                                                    const unsigned short* __restrict__ lb2b,  // [D][16]
                                                    const int* __restrict__ gidx,
                                                    float* __restrict__ ylora) {
  const int t = blockIdx.x;
  const int tid = threadIdx.x;
  const float* qr = qw + (size_t)t * 32;
  float q1[16], q2[16];
  #pragma unroll
  for (int r = 0; r < 16; ++r) { q1[r] = qr[r]; q2[r] = qr[16 + r]; }
  if (t < NMOE) {
    const unsigned short* p1 = B2b + (size_t)gidx[t * 2] * D * 16;
    const unsigned short* p2 = B2b + (size_t)gidx[t * 2 + 1] * D * 16;
    #pragma unroll
    for (int i = 0; i < 8; ++i) {
      int d = tid + i * 256;
      ylora[(size_t)t * D + d] = dot16bf(q1, p1 + d * 16) + dot16bf(q2, p2 + d * 16);
    }
  } else {
    #pragma unroll
    for (int i = 0; i < 8; ++i) {
      int d = tid + i * 256;
      ylora[(size_t)t * D + d] = dot16bf(q1, lb2b + d * 16);
    }
  }
}

// ---------------------------------------------------------------- host
extern "C" void kernel_launch(void* const* d_in, const int* in_sizes, int n_in,
                              void* d_out, int out_size, void* d_ws, size_t ws_size,
                              hipStream_t stream) {
  (void)in_sizes; (void)n_in; (void)out_size; (void)ws_size;
  const float* data = (const float*)d_in[0];
  const float* W1   = (const float*)d_in[1];
  const float* W3   = (const float*)d_in[2];
  const float* W2   = (const float*)d_in[3];
  const float* gW   = (const float*)d_in[4];
  const float* A1   = (const float*)d_in[5];
  const float* B1   = (const float*)d_in[6];
  const float* A3   = (const float*)d_in[7];
  const float* B3   = (const float*)d_in[8];
  const float* A2   = (const float*)d_in[9];
  const float* B2   = (const float*)d_in[10];
  const float* la1  = (const float*)d_in[11];
  const float* lb1  = (const float*)d_in[12];
  const float* la3  = (const float*)d_in[13];
  const float* lb3  = (const float*)d_in[14];
  const float* la2  = (const float*)d_in[15];
  const float* lb2  = (const float*)d_in[16];

  char* w = (char*)d_ws;
  size_t off = 0;
  auto alloc = [&](size_t bytes) -> char* {
    char* p = w + off;
    off += (bytes + 255) & ~(size_t)255;
    return p;
  };
  unsigned short* xb    = (unsigned short*)alloc((size_t)NTOK * D * 2);       // 8.4 MB
  unsigned short* W13b  = (unsigned short*)alloc((size_t)NW * D * 2);         // 47.7 MB (W1|W3|LoRA-A|pad)
  unsigned short* W2b   = (unsigned short*)alloc((size_t)D * DFF * 2);        // 23.1 MB
  unsigned short* B1b   = (unsigned short*)alloc((size_t)8 * DFF * 16 * 2);
  unsigned short* B3b   = (unsigned short*)alloc((size_t)8 * DFF * 16 * 2);
  unsigned short* A2tb  = (unsigned short*)alloc((size_t)8 * DFF * 16 * 2);
  unsigned short* la2tb = (unsigned short*)alloc((size_t)DFF * 16 * 2);
  unsigned short* lb1b  = (unsigned short*)alloc((size_t)DFF * 16 * 2);
  unsigned short* lb3b  = (unsigned short*)alloc((size_t)DFF * 16 * 2);
  unsigned short* lb2b  = (unsigned short*)alloc((size_t)D * 16 * 2);
  unsigned short* B2b   = (unsigned short*)alloc((size_t)8 * D * 16 * 2);
  int*   gidx = (int*)alloc((size_t)NMOE * 2 * 4);
  float* gwt  = (float*)alloc((size_t)NMOE * 2 * 4);
  unsigned short* GU    = (unsigned short*)alloc((size_t)NTOK * NW * 2);      // 47.7 MB

  // Aliased scratch (regions dead after the up-GEMM):
  unsigned short* Hb = W13b;                                        // 23.07 MB into W1 region
  float* ylora = (float*)((char*)W13b + (size_t)NTOK * DFF * 2);    // 16.78 MB into W3 region
  float* qw    = (float*)xb;                                        // 0.26 MB

  // ---- prep casts (all n % 1024 == 0)
  CastSegs cs;
  const float* srcs[14] = {data, W1, W3, W2, A1, A3, la1, la3, B1, B3, lb1, lb3, lb2, B2};
  unsigned short* dsts[14] = {
      xb, W13b, W13b + (size_t)DFF * D, W2b,
      W13b + (size_t)COL_A1 * D, W13b + (size_t)COL_A3 * D,
      W13b + (size_t)COL_LA1 * D, W13b + (size_t)COL_LA3 * D,
      B1b, B3b, lb1b, lb3b, lb2b, B2b};
  int ns[14] = {NTOK * D, DFF * D, DFF * D, DFF * D, 128 * D, 128 * D, 16 * D, 16 * D,
                8 * DFF * 16, 8 * DFF * 16, DFF * 16, DFF * 16, D * 16, 8 * D * 16};
  int total_blocks = 0;
  for (int i = 0; i < 14; ++i) {
    cs.src[i] = srcs[i];
    cs.dst[i] = dsts[i];
    total_blocks += ns[i] / 1024;
    cs.blk_end[i] = total_blocks;
  }
  cast_segs_kernel<<<total_blocks, 256, 0, stream>>>(cs);
  transpose_ra_kernel<<<dim3(DFF / 256, 9), 256, 0, stream>>>(A2, la2, A2tb, la2tb);
  hipMemsetAsync(W13b + (size_t)11552 * D, 0, (size_t)(NW - 11552) * D * 2, stream);  // zero-pad rows

  // ---- gating (also writes logits output, f32)
  gate_kernel<<<NMOE / 4, 256, 0, stream>>>(data, gW,
      (float*)d_out + (size_t)NTOK * D, gidx, gwt);

  // ---- up-GEMM: [X | LoRA-A] fused, 2048 x 11648 x 2048, bf16 out -> GU
  // 128x128, 4 waves, dbuf 64KB -> 2 blocks/CU, minimal 2-barrier loop, grid 1456
  gemmM<128, 128, 2, 2, 2, 1><<<(NTOK / 128) * (NW / 128), 256, 0, stream>>>(
      xb, W13b, D, (float*)nullptr, GU, (const float*)nullptr, NW, NW / 128);

  // ---- h̄ / per-expert q  (writes Hb, qw — aliased into now-dead regions)
  h_kernel<<<NTOK, 256, 0, stream>>>(GU, B1b, B3b, A2tb, lb1b, lb3b, la2tb,
                                     gidx, gwt, Hb, qw);

  // ---- rank-16 down-LoRA correction
  ylora_kernel<<<NTOK, 256, 0, stream>>>(qw, B2b, lb2b, gidx, ylora);

  // ---- down-GEMM: 2048 x 2048 x 5632, epilogue adds y_lora, f32 -> d_out
  // 128x128, 4 waves, dbuf 64KB, minimal 2-barrier loop, grid 256
  gemmM<128, 128, 2, 2, 2, 2><<<(NTOK / 128) * (D / 128), 256, 0, stream>>>(
      Hb, W2b, DFF, (float*)d_out, (unsigned short*)nullptr, ylora, D, D / 128);
}

// Round 10
// 341.231 us; speedup vs baseline: 1.0606x; 1.0307x over previous
//
#include <hip/hip_runtime.h>
#include <hip/hip_bf16.h>

#define DEVI __device__ __forceinline__

typedef __attribute__((ext_vector_type(8))) short short8;   // 8 bf16 = 4 VGPRs (MFMA A/B frag)
typedef __attribute__((ext_vector_type(4))) float f32x4;    // MFMA C/D frag

constexpr int D    = 2048;
constexpr int DFF  = 5632;
constexpr int NTOK = 2048;   // total tokens (1024 MoE + 1024 dense)
constexpr int NMOE = 1024;
constexpr float KSCALE = 2.0f;  // 32/16

// up-GEMM N layout: [0,5632)=W1, [5632,11264)=W3, then LoRA-A columns:
constexpr int NW      = 11648;  // = 91*128
constexpr int COL_A1  = 11264;  // A1 stack: col = COL_A1 + e*16 + r
constexpr int COL_A3  = 11392;
constexpr int COL_LA1 = 11520;
constexpr int COL_LA3 = 11536;  // [11552,11648) zero-padded

DEVI float bf2f(unsigned short u) { return __uint_as_float(((unsigned)u) << 16); }
DEVI unsigned short f2bf(float f) {                       // round-to-nearest-even
  unsigned u = __float_as_uint(f);
  u += 0x7FFFu + ((u >> 16) & 1u);
  return (unsigned short)(u >> 16);
}
DEVI float silu(float x) { return x / (1.f + __expf(-x)); }

// ---------------------------------------------------------------- prep: f32->bf16 casts
struct CastSegs {
  const float* src[14];
  unsigned short* dst[14];
  int blk_end[14];   // exclusive prefix sums of per-segment block counts
};

__global__ __launch_bounds__(256) void cast_segs_kernel(CastSegs cs) {
  int b = blockIdx.x;
  int s = 0;
  #pragma unroll
  for (int i = 0; i < 14; ++i) if (b >= cs.blk_end[i]) s = i + 1;
  int bstart = (s == 0) ? 0 : cs.blk_end[s - 1];
  size_t idx = ((size_t)(b - bstart) * 256 + threadIdx.x) * 4;   // every segment n % 1024 == 0
  float4 v = *(const float4*)(cs.src[s] + idx);
  ushort4 o;
  o.x = f2bf(v.x); o.y = f2bf(v.y); o.z = f2bf(v.z); o.w = f2bf(v.w);
  *(ushort4*)(cs.dst[s] + idx) = o;
}

// A2 (E,R,DFF) -> A2t (E,DFF,R) bf16 ; la2 (R,DFF) -> la2t (DFF,R) bf16
__global__ __launch_bounds__(256) void transpose_ra_kernel(const float* __restrict__ A2,
                                                           const float* __restrict__ la2,
                                                           unsigned short* __restrict__ A2tb,
                                                           unsigned short* __restrict__ la2tb) {
  int f = blockIdx.x * 256 + threadIdx.x;          // 0..5631 (grid.x=22 exact)
  int e = blockIdx.y;                              // 0..7 = A2 expert, 8 = la2
  const float* src = (e < 8) ? (A2 + (size_t)e * 16 * DFF) : la2;
  unsigned short* dst = (e < 8) ? (A2tb + (size_t)e * DFF * 16) : la2tb;
  unsigned short tmp[16];
  #pragma unroll
  for (int r = 0; r < 16; ++r) tmp[r] = f2bf(src[(size_t)r * DFF + f]);
  #pragma unroll
  for (int r = 0; r < 16; ++r) dst[(size_t)f * 16 + r] = tmp[r];
}

// ---------------------------------------------------------------- gating (exact f32)
__global__ __launch_bounds__(256) void gate_kernel(const float* __restrict__ x,
                                                   const float* __restrict__ gW,
                                                   float* __restrict__ logits_out,
                                                   int* __restrict__ gidx,
                                                   float* __restrict__ gwt) {
  int t = blockIdx.x * 4 + (threadIdx.x >> 6);     // one wave per token, 1024 tokens
  int lane = threadIdx.x & 63;
  const float* xr = x + (size_t)t * D;
  float acc[8];
  #pragma unroll
  for (int e = 0; e < 8; ++e) acc[e] = 0.f;
  for (int k = lane; k < D; k += 64) {
    float xv = xr[k];
    #pragma unroll
    for (int e = 0; e < 8; ++e) acc[e] = fmaf(xv, gW[e * D + k], acc[e]);
  }
  #pragma unroll
  for (int e = 0; e < 8; ++e) {
    float v = acc[e];
    #pragma unroll
    for (int s = 32; s > 0; s >>= 1) v += __shfl_xor(v, s);
    acc[e] = v;
  }
  if (lane == 0) {
    #pragma unroll
    for (int e = 0; e < 8; ++e) logits_out[(size_t)t * 8 + e] = acc[e];
    int i1 = 0;
    #pragma unroll
    for (int e = 1; e < 8; ++e) if (acc[e] > acc[i1]) i1 = e;   // ties -> lowest index (jax)
    int i2 = (i1 == 0) ? 1 : 0;
    #pragma unroll
    for (int e = 0; e < 8; ++e) if (e != i1 && acc[e] > acc[i2]) i2 = e;
    float w1 = 1.f / (1.f + expf(acc[i2] - acc[i1]));           // p1/(p1+p2), stable
    gidx[t * 2] = i1; gidx[t * 2 + 1] = i2;
    gwt[t * 2] = w1;  gwt[t * 2 + 1] = 1.f - w1;
  }
}

// ---------------------------------------------------------------- minimal-barrier bf16 GEMM
// C = A(M,K) * B(N,K)^T.  BK=64, per-wave 64x64 output, double-buffered LDS,
// per K-tile: {stage all 8 loads of tile t+1 -> counted vmcnt(8) -> barrier ->
// [16 ds_read + 32 MFMA, compiler-scheduled, NO pinning] -> barrier}.
// XOR-swizzled LDS (granule^row&7, inverse applied on global source) -> 0 conflicts.
// by-FASTEST traversal: consecutive blocks share the B-panel (L2-resident).
// EPI: 1 -> bf16 store; 2 -> f32 store (+addv).
typedef const void __attribute__((address_space(1)))* gp1_t;
typedef void __attribute__((address_space(3)))* lp3_t;
DEVI void gload_lds16(const void* g, void* l) {
  __builtin_amdgcn_global_load_lds((gp1_t)g, (lp3_t)l, 16, 0, 0);
}
#define S_BARRIER() asm volatile("s_barrier" ::: "memory")

template <int N> DEVI void vmcnt_() {
  static_assert(N == 0 || N == 8, "enumerate literals");
  if constexpr (N == 0) asm volatile("s_waitcnt vmcnt(0)" ::: "memory");
  if constexpr (N == 8) asm volatile("s_waitcnt vmcnt(8)" ::: "memory");
}

template <int BM, int BN, int WM, int WN, int MINW, int EPI>
__global__ __launch_bounds__(WM * WN * 64, MINW) void gemmM(
    const unsigned short* __restrict__ A,
    const unsigned short* __restrict__ B,
    int K,
    float* __restrict__ Cf,
    unsigned short* __restrict__ Cb,
    const float* __restrict__ addv,
    int ldc, int nby) {
  constexpr int THREADS = WM * WN * 64;
  constexpr int RW = BM / WM;              // 64
  constexpr int CW = BN / WN;              // 64
  static_assert(RW == 64 && CW == 64, "template assumes 64x64 per-wave tile");
  constexpr int ATILE = BM * 128;          // bytes (BM x 64 bf16)
  constexpr int BTILE = BN * 128;
  constexpr int SLOT = ATILE + BTILE;
  constexpr int APARTS = BM * 8 / THREADS; // 16B chunks per thread for A
  constexpr int BPARTS = BN * 8 / THREADS;
  static_assert(APARTS + BPARTS == 8, "vmcnt gate literal assumes 8 loads/tile");

  __shared__ __align__(16) char smem[2 * SLOT];

  const int tid = threadIdx.x;
  const int wave = tid >> 6, lane = tid & 63;
  const int wm = wave / WN, wn = wave % WN;
  const int r15 = lane & 15, g = lane >> 4;

  // XCD-aware bijective block swizzle (nwg % 8 == 0 for all our launches)
  const int nwg = (int)gridDim.x;
  const int bid = (int)blockIdx.x;
  const int wgid = (bid & 7) * (nwg >> 3) + (bid >> 3);
  // by-fastest: consecutive wgids share bx (B-panel stays L2-resident)
  const int by = wgid % nby, bx = wgid / nby;

  const unsigned short* Ablk = A + (size_t)by * BM * K;
  const unsigned short* Bblk = B + (size_t)bx * BN * K;

  // staging precompute: thread covers 16B chunk tt=j*THREADS+tid; row=tt>>3;
  // global source col pre-inverse-swizzled so linear LDS dest + swizzled read match.
  int sgoA[APARTS], sgoB[BPARTS];
  #pragma unroll
  for (int j = 0; j < APARTS; ++j) {
    int tt = j * THREADS + tid;
    int row = tt >> 3;
    sgoA[j] = row * K + (((tt & 7) ^ (row & 7)) << 3);
  }
  #pragma unroll
  for (int j = 0; j < BPARTS; ++j) {
    int tt = j * THREADS + tid;
    int row = tt >> 3;
    sgoB[j] = row * K + (((tt & 7) ^ (row & 7)) << 3);
  }
  auto stage = [&](int p, int k0) {
    char* s = smem + p * SLOT;
    #pragma unroll
    for (int j = 0; j < APARTS; ++j)
      gload_lds16((const char*)Ablk + ((size_t)(sgoA[j] + k0) << 1),
                  s + j * (THREADS * 16) + wave * 1024);
    #pragma unroll
    for (int j = 0; j < BPARTS; ++j)
      gload_lds16((const char*)Bblk + ((size_t)(sgoB[j] + k0) << 1),
                  s + ATILE + j * (THREADS * 16) + wave * 1024);
  };

  // ds_read addressing (swizzled): row*128 + ((granule ^ (row&7))<<4)
  const int arow0 = (wm * RW + r15) * 128;
  const int brow0 = (wn * CW + r15) * 128;
  const int s0 = ((g ^ (r15 & 7)) << 4);
  const int s1 = (((4 + g) ^ (r15 & 7)) << 4);

  f32x4 acc[4][4];
  #pragma unroll
  for (int m = 0; m < 4; ++m)
    #pragma unroll
    for (int n = 0; n < 4; ++n)
      #pragma unroll
      for (int j = 0; j < 4; ++j) acc[m][n][j] = 0.f;

  const int NT = K >> 6;

  stage(0, 0);                              // prologue: tile 0 -> buf 0

  for (int t = 0; t < NT; ++t) {
    const int p = t & 1;
    if (t + 1 < NT) {
      stage(p ^ 1, (t + 1) << 6);           // 8 loads for tile t+1 (into freed buf)
      vmcnt_<8>();                          // tile t fully landed (8 newest = t+1's)
    } else {
      vmcnt_<0>();
    }
    S_BARRIER();                            // all waves: buf p valid

    const char* sA = smem + p * SLOT;
    const char* sB = sA + ATILE;

    // reads + MFMA, unpinned: compiler interleaves with fine-grained lgkmcnt
    short8 bq[4][2], av[4][2];
    #pragma unroll
    for (int n = 0; n < 4; ++n) {
      bq[n][0] = *(const short8*)(sB + brow0 + n * 2048 + s0);
      bq[n][1] = *(const short8*)(sB + brow0 + n * 2048 + s1);
    }
    #pragma unroll
    for (int m = 0; m < 4; ++m) {
      av[m][0] = *(const short8*)(sA + arow0 + m * 2048 + s0);
      av[m][1] = *(const short8*)(sA + arow0 + m * 2048 + s1);
    }
    #pragma unroll
    for (int m = 0; m < 4; ++m)
      #pragma unroll
      for (int n = 0; n < 4; ++n)
        #pragma unroll
        for (int kk = 0; kk < 2; ++kk)
          acc[m][n] = __builtin_amdgcn_mfma_f32_16x16x32_bf16(
              av[m][kk], bq[n][kk], acc[m][n], 0, 0, 0);

    S_BARRIER();                            // reads of buf p done before overwrite
  }

  // epilogue: C/D layout col=lane&15, row=(lane>>4)*4+reg  [m89-verified]
  const int row0 = by * BM + wm * RW + (g << 2);
  const int col0 = bx * BN + wn * CW + r15;
  #pragma unroll
  for (int m = 0; m < 4; ++m) {
    #pragma unroll
    for (int n = 0; n < 4; ++n) {
      int col = col0 + n * 16;
      #pragma unroll
      for (int j = 0; j < 4; ++j) {
        int row = row0 + m * 16 + j;
        size_t off = (size_t)row * ldc + col;
        float v = acc[m][n][j];
        if (EPI == 1) Cb[off] = f2bf(v);
        else          Cf[off] = v + addv[off];
      }
    }
  }
}

// ---------------------------------------------------------------- h / combine / q kernel
DEVI float dot16bf(const float* a, const unsigned short* w) {
  short8 w0 = *(const short8*)w;
  short8 w1 = *(const short8*)(w + 8);
  float s = 0.f;
  #pragma unroll
  for (int i = 0; i < 8; ++i) s = fmaf(a[i],     bf2f((unsigned short)w0[i]), s);
  #pragma unroll
  for (int i = 0; i < 8; ++i) s = fmaf(a[8 + i], bf2f((unsigned short)w1[i]), s);
  return s;
}

__global__ __launch_bounds__(256) void h_kernel(
    const unsigned short* __restrict__ GU,      // [NTOK][NW] bf16
    const unsigned short* __restrict__ B1b,     // [8][DFF][16]
    const unsigned short* __restrict__ B3b,
    const unsigned short* __restrict__ A2tb,    // [8][DFF][16]
    const unsigned short* __restrict__ lb1b,    // [DFF][16]
    const unsigned short* __restrict__ lb3b,
    const unsigned short* __restrict__ la2tb,   // [DFF][16]
    const int* __restrict__ gidx, const float* __restrict__ gwt,
    unsigned short* __restrict__ Hb,            // [NTOK][DFF] bf16
    float* __restrict__ qw) {                   // [NTOK][32]
  const int t = blockIdx.x;
  const int tid = threadIdx.x;
  const unsigned short* gu = GU + (size_t)t * NW;
  unsigned short* hrow = Hb + (size_t)t * DFF;
  float qacc[32];
  #pragma unroll
  for (int r = 0; r < 32; ++r) qacc[r] = 0.f;
  float w1 = 0.f, w2 = 0.f;

  if (t < NMOE) {
    const int e1 = gidx[t * 2], e2 = gidx[t * 2 + 1];
    w1 = gwt[t * 2]; w2 = gwt[t * 2 + 1];
    float xa1a[16], xa1b[16], xa3a[16], xa3b[16];
    #pragma unroll
    for (int r = 0; r < 16; ++r) {
      xa1a[r] = bf2f(gu[COL_A1 + e1 * 16 + r]);
      xa1b[r] = bf2f(gu[COL_A1 + e2 * 16 + r]);
      xa3a[r] = bf2f(gu[COL_A3 + e1 * 16 + r]);
      xa3b[r] = bf2f(gu[COL_A3 + e2 * 16 + r]);
    }
    const unsigned short* B1e1 = B1b + (size_t)e1 * DFF * 16;
    const unsigned short* B1e2 = B1b + (size_t)e2 * DFF * 16;
    const unsigned short* B3e1 = B3b + (size_t)e1 * DFF * 16;
    const unsigned short* B3e2 = B3b + (size_t)e2 * DFF * 16;
    const unsigned short* A2e1 = A2tb + (size_t)e1 * DFF * 16;
    const unsigned short* A2e2 = A2tb + (size_t)e2 * DFF * 16;
    for (int i = 0; i < 22; ++i) {
      int f = tid + i * 256;
      float bg = bf2f(gu[f]), bu = bf2f(gu[DFF + f]);
      float dg1 = dot16bf(xa1a, B1e1 + f * 16);
      float du1 = dot16bf(xa3a, B3e1 + f * 16);
      float dg2 = dot16bf(xa1b, B1e2 + f * 16);
      float du2 = dot16bf(xa3b, B3e2 + f * 16);
      float h1 = silu(bg + KSCALE * dg1) * (bu + KSCALE * du1);
      float h2 = silu(bg + KSCALE * dg2) * (bu + KSCALE * du2);
      hrow[f] = f2bf(w1 * h1 + w2 * h2);
      short8 a0 = *(const short8*)(A2e1 + f * 16);
      short8 a1 = *(const short8*)(A2e1 + f * 16 + 8);
      short8 b0 = *(const short8*)(A2e2 + f * 16);
      short8 b1 = *(const short8*)(A2e2 + f * 16 + 8);
      #pragma unroll
      for (int r = 0; r < 8; ++r) {
        qacc[r]      = fmaf(h1, bf2f((unsigned short)a0[r]), qacc[r]);
        qacc[8 + r]  = fmaf(h1, bf2f((unsigned short)a1[r]), qacc[8 + r]);
        qacc[16 + r] = fmaf(h2, bf2f((unsigned short)b0[r]), qacc[16 + r]);
        qacc[24 + r] = fmaf(h2, bf2f((unsigned short)b1[r]), qacc[24 + r]);
      }
    }
  } else {
    float s1[16], s3[16];
    #pragma unroll
    for (int r = 0; r < 16; ++r) {
      s1[r] = bf2f(gu[COL_LA1 + r]);
      s3[r] = bf2f(gu[COL_LA3 + r]);
    }
    for (int i = 0; i < 22; ++i) {
      int f = tid + i * 256;
      float bg = bf2f(gu[f]), bu = bf2f(gu[DFF + f]);
      float dg = dot16bf(s1, lb1b + f * 16);
      float du = dot16bf(s3, lb3b + f * 16);
      float h = silu(bg + KSCALE * dg) * (bu + KSCALE * du);
      hrow[f] = f2bf(h);
      short8 a0 = *(const short8*)(la2tb + f * 16);
      short8 a1 = *(const short8*)(la2tb + f * 16 + 8);
      #pragma unroll
      for (int r = 0; r < 8; ++r) {
        qacc[r]     = fmaf(h, bf2f((unsigned short)a0[r]), qacc[r]);
        qacc[8 + r] = fmaf(h, bf2f((unsigned short)a1[r]), qacc[8 + r]);
      }
    }
  }

  // reduce 32 partials across 256 threads
  #pragma unroll
  for (int r = 0; r < 32; ++r) {
    float v = qacc[r];
    #pragma unroll
    for (int s = 32; s > 0; s >>= 1) v += __shfl_xor(v, s);
    qacc[r] = v;
  }
  __shared__ float red[4][32];
  const int wave = tid >> 6, lane = tid & 63;
  if (lane == 0) {
    #pragma unroll
    for (int r = 0; r < 32; ++r) red[wave][r] = qacc[r];
  }
  __syncthreads();
  if (tid < 32) {
    float v = red[0][tid] + red[1][tid] + red[2][tid] + red[3][tid];
    float sc = (t < NMOE) ? ((tid < 16) ? (KSCALE * w1) : (KSCALE * w2)) : KSCALE;
    qw[(size_t)t * 32 + tid] = v * sc;
  }
}

// ---------------------------------------------------------------- rank-16 down-LoRA -> y_lora f32
__global__ __launch_bounds__(256) void ylora_kernel(const float* __restrict__ qw,
                                                    const unsigned short* __restrict__ B2b,   // [8][D][16]
                                                    const unsigned short* __restrict__ lb2b,  // [D][16]
                                                    const int* __restrict__ gidx,
                                                    float* __restrict__ ylora) {
  const int t = blockIdx.x;
  const int tid = threadIdx.x;
  const float* qr = qw + (size_t)t * 32;
  float q1[16], q2[16];
  #pragma unroll
  for (int r = 0; r < 16; ++r) { q1[r] = qr[r]; q2[r] = qr[16 + r]; }
  if (t < NMOE) {
    const unsigned short* p1 = B2b + (size_t)gidx[t * 2] * D * 16;
    const unsigned short* p2 = B2b + (size_t)gidx[t * 2 + 1] * D * 16;
    #pragma unroll
    for (int i = 0; i < 8; ++i) {
      int d = tid + i * 256;
      ylora[(size_t)t * D + d] = dot16bf(q1, p1 + d * 16) + dot16bf(q2, p2 + d * 16);
    }
  } else {
    #pragma unroll
    for (int i = 0; i < 8; ++i) {
      int d = tid + i * 256;
      ylora[(size_t)t * D + d] = dot16bf(q1, lb2b + d * 16);
    }
  }
}

// ---------------------------------------------------------------- host
extern "C" void kernel_launch(void* const* d_in, const int* in_sizes, int n_in,
                              void* d_out, int out_size, void* d_ws, size_t ws_size,
                              hipStream_t stream) {
  (void)in_sizes; (void)n_in; (void)out_size; (void)ws_size;
  const float* data = (const float*)d_in[0];
  const float* W1   = (const float*)d_in[1];
  const float* W3   = (const float*)d_in[2];
  const float* W2   = (const float*)d_in[3];
  const float* gW   = (const float*)d_in[4];
  const float* A1   = (const float*)d_in[5];
  const float* B1   = (const float*)d_in[6];
  const float* A3   = (const float*)d_in[7];
  const float* B3   = (const float*)d_in[8];
  const float* A2   = (const float*)d_in[9];
  const float* B2   = (const float*)d_in[10];
  const float* la1  = (const float*)d_in[11];
  const float* lb1  = (const float*)d_in[12];
  const float* la3  = (const float*)d_in[13];
  const float* lb3  = (const float*)d_in[14];
  const float* la2  = (const float*)d_in[15];
  const float* lb2  = (const float*)d_in[16];

  char* w = (char*)d_ws;
  size_t off = 0;
  auto alloc = [&](size_t bytes) -> char* {
    char* p = w + off;
    off += (bytes + 255) & ~(size_t)255;
    return p;
  };
  unsigned short* xb    = (unsigned short*)alloc((size_t)NTOK * D * 2);       // 8.4 MB
  unsigned short* W13b  = (unsigned short*)alloc((size_t)NW * D * 2);         // 47.7 MB (W1|W3|LoRA-A|pad)
  unsigned short* W2b   = (unsigned short*)alloc((size_t)D * DFF * 2);        // 23.1 MB
  unsigned short* B1b   = (unsigned short*)alloc((size_t)8 * DFF * 16 * 2);
  unsigned short* B3b   = (unsigned short*)alloc((size_t)8 * DFF * 16 * 2);
  unsigned short* A2tb  = (unsigned short*)alloc((size_t)8 * DFF * 16 * 2);
  unsigned short* la2tb = (unsigned short*)alloc((size_t)DFF * 16 * 2);
  unsigned short* lb1b  = (unsigned short*)alloc((size_t)DFF * 16 * 2);
  unsigned short* lb3b  = (unsigned short*)alloc((size_t)DFF * 16 * 2);
  unsigned short* lb2b  = (unsigned short*)alloc((size_t)D * 16 * 2);
  unsigned short* B2b   = (unsigned short*)alloc((size_t)8 * D * 16 * 2);
  int*   gidx = (int*)alloc((size_t)NMOE * 2 * 4);
  float* gwt  = (float*)alloc((size_t)NMOE * 2 * 4);
  unsigned short* GU    = (unsigned short*)alloc((size_t)NTOK * NW * 2);      // 47.7 MB

  // Aliased scratch (regions dead after the up-GEMM):
  unsigned short* Hb = W13b;                                        // 23.07 MB into W1 region
  float* ylora = (float*)((char*)W13b + (size_t)NTOK * DFF * 2);    // 16.78 MB into W3 region
  float* qw    = (float*)xb;                                        // 0.26 MB

  // ---- prep casts (all n % 1024 == 0)
  CastSegs cs;
  const float* srcs[14] = {data, W1, W3, W2, A1, A3, la1, la3, B1, B3, lb1, lb3, lb2, B2};
  unsigned short* dsts[14] = {
      xb, W13b, W13b + (size_t)DFF * D, W2b,
      W13b + (size_t)COL_A1 * D, W13b + (size_t)COL_A3 * D,
      W13b + (size_t)COL_LA1 * D, W13b + (size_t)COL_LA3 * D,
      B1b, B3b, lb1b, lb3b, lb2b, B2b};
  int ns[14] = {NTOK * D, DFF * D, DFF * D, DFF * D, 128 * D, 128 * D, 16 * D, 16 * D,
                8 * DFF * 16, 8 * DFF * 16, DFF * 16, DFF * 16, D * 16, 8 * D * 16};
  int total_blocks = 0;
  for (int i = 0; i < 14; ++i) {
    cs.src[i] = srcs[i];
    cs.dst[i] = dsts[i];
    total_blocks += ns[i] / 1024;
    cs.blk_end[i] = total_blocks;
  }
  cast_segs_kernel<<<total_blocks, 256, 0, stream>>>(cs);
  transpose_ra_kernel<<<dim3(DFF / 256, 9), 256, 0, stream>>>(A2, la2, A2tb, la2tb);
  hipMemsetAsync(W13b + (size_t)11552 * D, 0, (size_t)(NW - 11552) * D * 2, stream);  // zero-pad rows

  // ---- gating (also writes logits output, f32)
  gate_kernel<<<NMOE / 4, 256, 0, stream>>>(data, gW,
      (float*)d_out + (size_t)NTOK * D, gidx, gwt);

  // ---- up-GEMM: [X | LoRA-A] fused, 2048 x 11648 x 2048, bf16 out -> GU
  // 128x128, 4 waves, dbuf 64KB -> 2 blocks/CU, 2-barrier loop, by-fastest traversal
  gemmM<128, 128, 2, 2, 2, 1><<<(NTOK / 128) * (NW / 128), 256, 0, stream>>>(
      xb, W13b, D, (float*)nullptr, GU, (const float*)nullptr, NW, NTOK / 128);

  // ---- h̄ / per-expert q  (writes Hb, qw — aliased into now-dead regions)
  h_kernel<<<NTOK, 256, 0, stream>>>(GU, B1b, B3b, A2tb, lb1b, lb3b, la2tb,
                                     gidx, gwt, Hb, qw);

  // ---- rank-16 down-LoRA correction
  ylora_kernel<<<NTOK, 256, 0, stream>>>(qw, B2b, lb2b, gidx, ylora);

  // ---- down-GEMM: 2048 x 2048 x 5632, epilogue adds y_lora, f32 -> d_out
  // 128x128, 4 waves, dbuf 64KB, 2-barrier loop, by-fastest traversal, grid 256
  gemmM<128, 128, 2, 2, 2, 2><<<(NTOK / 128) * (D / 128), 256, 0, stream>>>(
      Hb, W2b, DFF, (float*)d_out, (unsigned short*)nullptr, ylora, D, NTOK / 128);
}